// Round 2
// baseline (468.393 us; speedup 1.0000x reference)
//
#include <hip/hip_runtime.h>
#include <hip/hip_bf16.h>

// AdaptiveReLULayer: out[b,n,o] = leaky( sum_i x[b,n,i] * weight[idx[b],i,o] + bias[o], 0.2 )
// B=2048, N=256, IN=256, OUT=256, C=1024.  f32 I/O; bf16 MFMA, f32 accum.
//
// R5 change vs R4 (307us -- IDENTICAL to R3 despite halved LDS/VALU):
// R3==R4 proves the K-loop internals are off the critical path. The binder is
// the barrier-lockstep convoy: all ~512 resident blocks burst 32KB of loads,
// then convoy through s_barrier at HBM queue-drain rate (16MB/round / 6.3TBps
// = 2.6us = 6.2Kcy == measured 6.4Kcy/round), leaving HBM ~50% idle (3.1 of
// 6.3 TB/s). Fix: WAVE-AUTONOMOUS, ZERO-BARRIER streaming:
//   * A (x): direct global->fragment (x is k-contiguous; 8x dwordx4 + 16 pk2
//     per K-step), no A-LDS at all. wc-pair waves re-read rows -> L1/L2 hit.
//   * B (w): per-wave PRIVATE LDS B^T tile (64o x 32k bf16), double-buffered
//     2x4KB/wave = 32KB/block. Same wave produces and consumes -> ordering is
//     in-wave vmcnt/lgkmcnt only; compiler's counted waits are exact.
//   * NO s_barrier / __syncthreads anywhere. Waves self-pace; HBM queue
//     stays continuously fed.
// B^T layout: byte(o,k) = (o>>1)*128 + slot*16 + (k&7)*2,
//             slot = ((k>>3)*2 + (o&1)) ^ ((o>>1)&7)
// -> ds_read_b128: 8 lanes/bank-quad uniform (ideal); writes 2x ideal (free).

#define N_DIM 256
#define K_DIM 256
#define O_DIM 256

typedef __attribute__((ext_vector_type(8))) __bf16 bf16x8;
typedef __attribute__((ext_vector_type(4))) float f32x4;
typedef __attribute__((ext_vector_type(4))) unsigned int u32x4;

__device__ __forceinline__ f32x4 MFMA(u32x4 a, u32x4 b, f32x4 c) {
    return __builtin_amdgcn_mfma_f32_16x16x32_bf16(
        __builtin_bit_cast(bf16x8, a), __builtin_bit_cast(bf16x8, b), c, 0, 0, 0);
}

__device__ __forceinline__ unsigned pk2(float a, float b) {
    __hip_bfloat16 ha = __float2bfloat16(a);
    __hip_bfloat16 hb = __float2bfloat16(b);
    unsigned short sa, sb;
    __builtin_memcpy(&sa, &ha, 2);
    __builtin_memcpy(&sb, &hb, 2);
    return (unsigned)sa | ((unsigned)sb << 16);
}

__global__ __launch_bounds__(256) void argemm_kernel(
    const float* __restrict__ x,
    const int* __restrict__ idx,
    const float* __restrict__ w,
    const float* __restrict__ bias,
    float* __restrict__ out)
{
    __shared__ __align__(16) char lds[32768];  // 4 waves x (2 x 4KB B^T dbuf)

    const int tid = threadIdx.x;
    const int l   = tid & 63;
    const int wid = tid >> 6;
    const int wr  = wid >> 1;   // wave row (0..1) -> 64-row half
    const int wc  = wid & 1;    // wave col (0..1) -> 64-col half

    // XCD-chunked block swizzle (gridDim.x % 8 == 0)
    const unsigned bid     = blockIdx.x;
    const unsigned chunk   = gridDim.x >> 3;
    const unsigned logical = (bid & 7u) * chunk + (bid >> 3);
    const int b    = (int)(logical >> 2);
    const int tpos = (int)(logical & 3u);
    const int n0   = (tpos >> 1) * 128;
    const int o0   = (tpos & 1) * 128;

    const int c = idx[b];
    const float* xb = x + (size_t)b * (N_DIM * K_DIM);
    // this wave's 64-wide o-slice of the gathered weight tile
    const float* wv = w + (size_t)c * (K_DIM * O_DIM) + o0 + wc * 64;

    const int g = l >> 4;   // 0..3 (k-subgroup, also staging k-chunk)
    const int i = l & 15;   // 0..15 (frag row/col, also staging o-quad)

    // ---- per-wave LDS B^T region ----
    char* const ldsw = (char*)lds + wid * 8192;
    // read addr (o = n*16+i, k = g*8); n-term is a pure +n*1024 immediate
    const int bR = (i >> 1) * 128 + ((g * 2 + (i & 1)) ^ ((i >> 1) & 7)) * 16;
    // write addrs (o = i*4+j, k = g*8)
    int bW[4];
#pragma unroll
    for (int j = 0; j < 4; ++j) {
        const int orow = i * 4 + j;
        bW[j] = (orow >> 1) * 128 + ((g * 2 + (orow & 1)) ^ ((orow >> 1) & 7)) * 16;
    }

    // ---- A row pointers (direct global -> fragment) ----
    const float* xr[4];
#pragma unroll
    for (int m = 0; m < 4; ++m)
        xr[m] = xb + (n0 + wr * 64 + m * 16 + i) * K_DIM + g * 8;

    // ---- B staging base (k-row g*8+dk, o-quad i*4) ----
    const float* wp = wv + (g * 8) * O_DIM + i * 4;

    f32x4 ra[8], rb[8];

    auto issueA = [&](int t) {
#pragma unroll
        for (int m = 0; m < 4; ++m) {
            ra[2 * m]     = *(const f32x4*)(xr[m] + t * 32);
            ra[2 * m + 1] = *(const f32x4*)(xr[m] + t * 32 + 4);
        }
    };
    auto issueB = [&](int t) {
#pragma unroll
        for (int dk = 0; dk < 8; ++dk)
            rb[dk] = *(const f32x4*)(wp + (size_t)(t * 32 + dk) * O_DIM);
    };
    // cvt f32->bf16, transpose in reg, write B^T (waits its vmcnt via compiler)
    auto flushB = [&](int buf) {
        char* d = ldsw + buf * 4096;
#pragma unroll
        for (int j = 0; j < 4; ++j) {
            u32x4 p;
            p.x = pk2(rb[0][j], rb[1][j]);
            p.y = pk2(rb[2][j], rb[3][j]);
            p.z = pk2(rb[4][j], rb[5][j]);
            p.w = pk2(rb[6][j], rb[7][j]);
            *(u32x4*)(d + bW[j]) = p;
        }
    };

    f32x4 acc[4][4];
#pragma unroll
    for (int m = 0; m < 4; ++m)
#pragma unroll
        for (int n = 0; n < 4; ++n)
            acc[m][n] = (f32x4){0.f, 0.f, 0.f, 0.f};

    // prologue: B(0) -> LDS buf0; A(0), B(1) in flight.  NO barriers.
    issueB(0);
    issueA(0);
    flushB(0);
    issueB(1);

#pragma unroll
    for (int t = 0; t < 8; ++t) {
        const int cur = t & 1;

        // A fragments for tile t (compiler inserts counted vmcnt for ra)
        u32x4 af[4];
#pragma unroll
        for (int m = 0; m < 4; ++m) {
            af[m].x = pk2(ra[2 * m].x,     ra[2 * m].y);
            af[m].y = pk2(ra[2 * m].z,     ra[2 * m].w);
            af[m].z = pk2(ra[2 * m + 1].x, ra[2 * m + 1].y);
            af[m].w = pk2(ra[2 * m + 1].z, ra[2 * m + 1].w);
        }
        if (t < 7) {
            issueA(t + 1);        // ra dead after af extraction
            flushB(cur ^ 1);      // tile t+1 -> other buffer (no WAR with cur)
        }
        if (t < 6) issueB(t + 2);

        const char* s = ldsw + cur * 4096;
#pragma unroll
        for (int n = 0; n < 4; ++n) {
            const u32x4 bq = *(const u32x4*)(s + bR + n * 1024);
#pragma unroll
            for (int m = 0; m < 4; ++m)
                acc[m][n] = MFMA(af[m], bq, acc[m][n]);
        }
    }

    // ---- epilogue: bias + LeakyReLU(0.2), f32 store ----
    float biasf[4];
#pragma unroll
    for (int n = 0; n < 4; ++n)
        biasf[n] = bias[o0 + wc * 64 + n * 16 + i];

    float* ob = out + (size_t)b * (N_DIM * O_DIM);
#pragma unroll
    for (int m = 0; m < 4; ++m) {
#pragma unroll
        for (int r = 0; r < 4; ++r) {
            const int row = n0 + wr * 64 + m * 16 + g * 4 + r;
#pragma unroll
            for (int n = 0; n < 4; ++n) {
                float v = acc[m][n][r] + biasf[n];
                v = (v >= 0.f) ? v : 0.2f * v;
                ob[row * O_DIM + o0 + wc * 64 + n * 16 + i] = v;
            }
        }
    }
}

extern "C" void kernel_launch(void* const* d_in, const int* in_sizes, int n_in,
                              void* d_out, int out_size, void* d_ws, size_t ws_size,
                              hipStream_t stream) {
    const float* x    = (const float*)d_in[0];
    const int*   idx  = (const int*)d_in[1];
    const float* w    = (const float*)d_in[2];
    const float* bias = (const float*)d_in[3];
    float*       out  = (float*)d_out;
    (void)d_ws; (void)ws_size; (void)n_in; (void)out_size;

    const int B = in_sizes[1];          // 2048
    dim3 grid((unsigned)(B * 4)), block(256);
    hipLaunchKernelGGL(argemm_kernel, grid, block, 0, stream, x, idx, w, bias, out);
}

// Round 3
// 298.300 us; speedup vs baseline: 1.5702x; 1.5702x over previous
//
#include <hip/hip_runtime.h>
#include <hip/hip_bf16.h>

// AdaptiveReLULayer: out[b,n,o] = leaky( sum_i x[b,n,i] * weight[idx[b],i,o] + bias[o], 0.2 )
// B=2048, N=256, IN=256, OUT=256, C=1024.  f32 I/O; bf16 MFMA, f32 accum.
//
// R6 change vs R4 (307us) / R5 (468us, FAILED):
// R5's zero-barrier version regressed because the compiler SANK the prefetch
// loads to their use sites (VGPR=100 proves ra/rb never coexisted with acc),
// collapsing prefetch depth to 0 -> raw HBM latency exposed per K-step.
// R6 keeps R4's proven skeleton (reg-staged f32->bf16, swizzled bf16 LDS,
// one s_barrier per K-step) and makes ONE change: a TWO-ROUND in-flight
// window for global loads:
//   * two named register staging sets (tile k -> set k&1)
//   * triple-buffered LDS (3 x 16KB; tile t -> buf t%3)
//   * round t: compute(t); flush(t+1) [loads issued at t-2: 2-round slack];
//              issue(t+3); lgkmcnt(0); s_barrier
//   * sched_barrier(0) after every issue group: forbids the scheduler from
//     sinking the loads (the R5 failure mode, now fenced)
// Expected: flush's counted vmcnt stall ~0; HBM queue continuously fed;
// round period drops from ~6400cy toward HBM service (~3200-4000cy).

#define N_DIM 256
#define K_DIM 256
#define O_DIM 256
#define BK 32

typedef __attribute__((ext_vector_type(8))) __bf16 bf16x8;
typedef __attribute__((ext_vector_type(4))) float f32x4;
typedef __attribute__((ext_vector_type(4))) unsigned int u32x4;
typedef __attribute__((ext_vector_type(2))) unsigned int u32x2;

__device__ __forceinline__ f32x4 MFMA(u32x4 a, u32x4 b, f32x4 c) {
    return __builtin_amdgcn_mfma_f32_16x16x32_bf16(
        __builtin_bit_cast(bf16x8, a), __builtin_bit_cast(bf16x8, b), c, 0, 0, 0);
}

__device__ __forceinline__ unsigned pk2(float a, float b) {
    __hip_bfloat16 ha = __float2bfloat16(a);
    __hip_bfloat16 hb = __float2bfloat16(b);
    unsigned short sa, sb;
    __builtin_memcpy(&sa, &ha, 2);
    __builtin_memcpy(&sb, &hb, 2);
    return (unsigned)sa | ((unsigned)sb << 16);
}

// bf16 tile stored as 64 row-pairs x 128B.  (row, k) -> byte offset.
// chunk(16B) index pre-swizzle = (row&1)*4 + (k>>3), XOR'd with (row>>1)&7.
__device__ __forceinline__ int swz(int row, int k) {
    const int rp = row >> 1;
    const int ch = (((row & 1) << 2) + (k >> 3)) ^ (rp & 7);
    return rp * 128 + ch * 16 + (k & 7) * 2;
}

__global__ __launch_bounds__(256) void argemm_kernel(
    const float* __restrict__ x,
    const int* __restrict__ idx,
    const float* __restrict__ w,
    const float* __restrict__ bias,
    float* __restrict__ out)
{
    __shared__ __align__(16) char lds[49152];  // 3 x (A 8KB | B^T 8KB)

    const int tid = threadIdx.x;
    const int l   = tid & 63;
    const int wid = tid >> 6;
    const int wr  = wid >> 1;   // wave row (0..1) -> 64-row half
    const int wc  = wid & 1;    // wave col (0..1) -> 64-col half

    // XCD-chunked block swizzle (gridDim.x % 8 == 0)
    const unsigned bid     = blockIdx.x;
    const unsigned chunk   = gridDim.x >> 3;
    const unsigned logical = (bid & 7u) * chunk + (bid >> 3);
    const int b    = (int)(logical >> 2);
    const int tpos = (int)(logical & 3u);
    const int n0   = (tpos >> 1) * 128;
    const int o0   = (tpos & 1) * 128;

    const int c = idx[b];
    const float* xb = x + (size_t)b * (N_DIM * K_DIM);
    const float* wb = w + (size_t)c * (K_DIM * O_DIM);

    // ---- staging maps (identical to R4) ----
    const int lr3 = l >> 3, kc = l & 7;
    int gA[4], aW[4];
#pragma unroll
    for (int q = 0; q < 4; ++q) {
        const int rA = wid * 32 + q * 8 + lr3;         // 0..127
        gA[q] = (n0 + rA) * K_DIM + kc * 4;            // f32 elem offset
        aW[q] = swz(rA, kc * 4);                       // LDS byte (b64 write)
    }
    const int kq = tid >> 5;          // 0..7
    const int m4 = (tid & 31) * 4;    // o 0..124
    int gB[4], bW[4];
#pragma unroll
    for (int dk = 0; dk < 4; ++dk)
        gB[dk] = (kq * 4 + dk) * O_DIM + o0 + m4;      // f32 elem offset
#pragma unroll
    for (int j = 0; j < 4; ++j)
        bW[j] = swz(m4 + j, kq * 4);                   // B^T[o][k] byte (rel)

    // ---- fragment read addresses ----
    const int g = l >> 4;   // 0..3 (k-subgroup)
    const int i = l & 15;   // 0..15
    int aR[4], bR[4];
#pragma unroll
    for (int m = 0; m < 4; ++m) aR[m] = swz(wr * 64 + m * 16 + i, g * 8);
#pragma unroll
    for (int n = 0; n < 4; ++n) bR[n] = 8192 + swz(wc * 64 + n * 16 + i, g * 8);

    // ---- two named staging sets: tile k lives in set k&1 ----
    f32x4 ra[2][4], rb[2][4];

    auto issue = [&](int t, int s) {
#pragma unroll
        for (int q = 0; q < 4; ++q)
            ra[s][q] = *(const f32x4*)(xb + gA[q] + t * BK);
#pragma unroll
        for (int dk = 0; dk < 4; ++dk)
            rb[s][dk] = *(const f32x4*)(wb + gB[dk] + t * (BK * O_DIM));
    };
    // cvt f32->bf16 and write LDS buf t%3 (counted vmcnt inserted by compiler;
    // with 2-round slack it should be a non-stall)
    auto flush = [&](int t, int s) {
        char* base = (char*)lds + (t % 3) * 16384;
#pragma unroll
        for (int q = 0; q < 4; ++q) {
            u32x2 p;
            p.x = pk2(ra[s][q].x, ra[s][q].y);
            p.y = pk2(ra[s][q].z, ra[s][q].w);
            *(u32x2*)(base + aW[q]) = p;               // A[row][k], k-contig
        }
#pragma unroll
        for (int j = 0; j < 4; ++j) {
            u32x2 p;                                    // pack along k
            p.x = pk2(rb[s][0][j], rb[s][1][j]);
            p.y = pk2(rb[s][2][j], rb[s][3][j]);
            *(u32x2*)(base + 8192 + bW[j]) = p;        // B^T[o][k], k-contig
        }
    };

    f32x4 acc[4][4];
#pragma unroll
    for (int m = 0; m < 4; ++m)
#pragma unroll
        for (int n = 0; n < 4; ++n)
            acc[m][n] = (f32x4){0.f, 0.f, 0.f, 0.f};

    // prologue: tiles 0,1,2 in flight; tile0 flushed to buf0
    issue(0, 0);
    __builtin_amdgcn_sched_barrier(0);
    issue(1, 1);
    __builtin_amdgcn_sched_barrier(0);
    flush(0, 0);                       // waits only set0's 8 loads
    issue(2, 0);
    __builtin_amdgcn_sched_barrier(0);
    asm volatile("s_waitcnt lgkmcnt(0)" ::: "memory");
    __builtin_amdgcn_sched_barrier(0);
    __builtin_amdgcn_s_barrier();

#pragma unroll
    for (int t = 0; t < 8; ++t) {
        const char* base = (const char*)lds + (t % 3) * 16384;

        u32x4 af[4];
#pragma unroll
        for (int m = 0; m < 4; ++m)
            af[m] = *(const u32x4*)(base + aR[m]);     // 8 bf16, MFMA-ready
#pragma unroll
        for (int n = 0; n < 4; ++n) {
            const u32x4 bq = *(const u32x4*)(base + bR[n]);
#pragma unroll
            for (int m = 0; m < 4; ++m)
                acc[m][n] = MFMA(af[m], bq, acc[m][n]);
        }

        if (t < 7) {
            flush(t + 1, (t + 1) & 1); // loads issued 2 rounds ago -> no stall
            if (t < 5) {
                issue(t + 3, (t + 1) & 1);             // refill the freed set
                __builtin_amdgcn_sched_barrier(0);     // forbid load sinking
            }
            // LDS drained (reads retired + writes visible); globals stay in
            // flight across the barrier (2 tiles outstanding).
            asm volatile("s_waitcnt lgkmcnt(0)" ::: "memory");
            __builtin_amdgcn_sched_barrier(0);
            __builtin_amdgcn_s_barrier();
        }
    }

    // ---- epilogue: bias + LeakyReLU(0.2), f32 store ----
    float biasf[4];
#pragma unroll
    for (int n = 0; n < 4; ++n)
        biasf[n] = bias[o0 + wc * 64 + n * 16 + i];

    float* ob = out + (size_t)b * (N_DIM * O_DIM);
#pragma unroll
    for (int m = 0; m < 4; ++m) {
#pragma unroll
        for (int r = 0; r < 4; ++r) {
            const int row = n0 + wr * 64 + m * 16 + g * 4 + r;
#pragma unroll
            for (int n = 0; n < 4; ++n) {
                float v = acc[m][n][r] + biasf[n];
                v = (v >= 0.f) ? v : 0.2f * v;
                ob[row * O_DIM + o0 + wc * 64 + n * 16 + i] = v;
            }
        }
    }
}

extern "C" void kernel_launch(void* const* d_in, const int* in_sizes, int n_in,
                              void* d_out, int out_size, void* d_ws, size_t ws_size,
                              hipStream_t stream) {
    const float* x    = (const float*)d_in[0];
    const int*   idx  = (const int*)d_in[1];
    const float* w    = (const float*)d_in[2];
    const float* bias = (const float*)d_in[3];
    float*       out  = (float*)d_out;
    (void)d_ws; (void)ws_size; (void)n_in; (void)out_size;

    const int B = in_sizes[1];          // 2048
    dim3 grid((unsigned)(B * 4)), block(256);
    hipLaunchKernelGGL(argemm_kernel, grid, block, 0, stream, x, idx, w, bias, out);
}